// Round 9
// baseline (231.488 us; speedup 1.0000x reference)
//
#include <hip/hip_runtime.h>
#include <hip/hip_bf16.h>
#include <math.h>

namespace {

constexpr int B = 8, T = 2048, D = 256, H = 4, HD = 64, FF = 1024;
constexpr float QSCALE = 0.18033688f;   // 0.125 * log2(e)

typedef __attribute__((ext_vector_type(8))) short short8;
typedef __attribute__((ext_vector_type(4))) short s16x4;
typedef __attribute__((ext_vector_type(4))) float f32x4;

__device__ __forceinline__ short f2bf(float f) {
    __hip_bfloat16 h = __float2bfloat16(f);
    return *reinterpret_cast<short*>(&h);
}
__device__ __forceinline__ float exp2a(float x) {
    float r; asm("v_exp_f32 %0, %1" : "=v"(r) : "v"(x)); return r;
}
__device__ __forceinline__ unsigned cvtpk(float lo, float hi) {
    unsigned r; asm("v_cvt_pk_bf16_f32 %0, %1, %2" : "=v"(r) : "v"(lo), "v"(hi)); return r;
}
__device__ __forceinline__ void gload16(const void* g, void* l) {
    __builtin_amdgcn_global_load_lds(
        (const __attribute__((address_space(1))) void*)g,
        (__attribute__((address_space(3))) void*)l, 16, 0, 0);
}

// ---------------- K0: fp32 -> bf16 conversions (x + 4 weight matrices) -----
__global__ __launch_bounds__(256) void k_cvt(
        const float* __restrict__ x,  const float* __restrict__ wq,
        const float* __restrict__ wo, const float* __restrict__ w1,
        const float* __restrict__ w2,
        short* __restrict__ x16,  short* __restrict__ wq16,
        short* __restrict__ wo16, short* __restrict__ w116,
        short* __restrict__ w216) {
    const int N0 = 524288, N1 = 24576, N2 = 8192, N3 = 32768, N4 = 32768;
    const int total = N0 + N1 + N2 + N3 + N4;
    for (int i = blockIdx.x*256 + threadIdx.x; i < total; i += gridDim.x*256) {
        const float* s; short* d; int j = i;
        if (j < N0) { s = x; d = x16; }
        else { j -= N0;
            if (j < N1) { s = wq; d = wq16; }
            else { j -= N1;
                if (j < N2) { s = wo; d = wo16; }
                else { j -= N2;
                    if (j < N3) { s = w1; d = w116; }
                    else { j -= N3; s = w2; d = w216; }
                }
            }
        }
        float4 a = ((const float4*)s)[j*2], b2 = ((const float4*)s)[j*2+1];
        short8 o;
        o[0]=f2bf(a.x);  o[1]=f2bf(a.y);  o[2]=f2bf(a.z);  o[3]=f2bf(a.w);
        o[4]=f2bf(b2.x); o[5]=f2bf(b2.y); o[6]=f2bf(b2.z); o[7]=f2bf(b2.w);
        ((short8*)d)[j] = o;
    }
}

// ---------------- K_GEMM128: m97-style 128x128 tile, BK=64, gload_lds ------
// Linear LDS [128][64] bf16 per matrix; source pre-swizzle cb^=(row&7) so
// swizzled b128 reads are bank-spread (m173/m201 both-sides involution).
// MODE 0: qkv  by0..3 -> q/k rows (q prescaled); by4,5 -> v transposed
// MODE 2: ffn1 relu bf16 out [m][1024]
template<int MODE>
__global__ __launch_bounds__(256) void k_gemm128(
        const short* __restrict__ A, const short* __restrict__ W,
        const float* __restrict__ bias, const int K,
        short* __restrict__ oq, short* __restrict__ ok, short* __restrict__ ov,
        short* __restrict__ o16) {
    __shared__ char pool[34048];                 // max(2*16384, 64*133*4)
    short* Asl = (short*)pool;                   // [128][64] linear, swizzled
    short* Wsl = (short*)(pool + 16384);
    float (*Cs)[133] = (float(*)[133])pool;

    const int tid = threadIdx.x;
    const int w = tid >> 6, lane = tid & 63;
    const int qr = lane & 15, g = lane >> 4;
    const int wm = w >> 1, wn = w & 1;
    const int m0 = blockIdx.x * 128;
    const int n0 = blockIdx.y * 128;
    const int srow = lane >> 3;                  // 0..7 within chunk
    const int scb  = (lane & 7) ^ srow;          // pre-swizzled source colblock

    f32x4 acc[4][4];
    #pragma unroll
    for (int i = 0; i < 4; i++)
        #pragma unroll
        for (int j = 0; j < 4; j++) acc[i][j] = (f32x4){0.f, 0.f, 0.f, 0.f};

    for (int k0 = 0; k0 < K; k0 += 64) {
        __syncthreads();                         // prior-iter reads done
        #pragma unroll
        for (int i = 0; i < 4; i++) {
            const int chunk = i*4 + w;
            const int row = chunk*8 + srow;
            gload16(A + (size_t)(m0 + row)*K + k0 + scb*8, Asl + chunk*512);
            gload16(W + (size_t)(n0 + row)*K + k0 + scb*8, Wsl + chunk*512);
        }
        __syncthreads();                         // vmcnt(0) drained by compiler
        #pragma unroll
        for (int kk = 0; kk < 2; kk++) {
            const int swz = ((g + 4*kk) ^ (qr & 7)) * 8;
            short8 af[4], bf[4];
            #pragma unroll
            for (int fm = 0; fm < 4; fm++)
                af[fm] = *(const short8*)(Asl + (wm*64 + fm*16 + qr)*64 + swz);
            #pragma unroll
            for (int fn = 0; fn < 4; fn++)
                bf[fn] = *(const short8*)(Wsl + (wn*64 + fn*16 + qr)*64 + swz);
            #pragma unroll
            for (int fm = 0; fm < 4; fm++)
                #pragma unroll
                for (int fn = 0; fn < 4; fn++)
                    acc[fm][fn] = __builtin_amdgcn_mfma_f32_16x16x32_bf16(
                        af[fm], bf[fn], acc[fm][fn], 0, 0, 0);
        }
    }

    const int b = m0 >> 11;
    const int tl0 = m0 & (T - 1);

    if (MODE == 0 && blockIdx.y >= 4) {
        // V tiles: write transposed vT[bh][d][t] direct from fragments
        #pragma unroll
        for (int fm = 0; fm < 4; fm++) {
            const int tl = tl0 + wm*64 + fm*16 + g*4;
            #pragma unroll
            for (int fn = 0; fn < 4; fn++) {
                const int nv = (n0 - 512) + wn*64 + fn*16 + qr;
                const int h = nv >> 6, d = nv & 63;
                const float bv = bias[n0 + wn*64 + fn*16 + qr];
                s16x4 pk;
                #pragma unroll
                for (int r = 0; r < 4; r++) pk[r] = f2bf(acc[fm][fn][r] + bv);
                *(s16x4*)&ov[((size_t)(b*H + h)*HD + d)*T + tl] = pk;
            }
        }
        return;
    }

    // epilogue via Cs, two 64-row halves
    __syncthreads();
    const int erow = tid & 63, c0 = (tid >> 6) * 32;
    #pragma unroll
    for (int hh = 0; hh < 2; hh++) {
        if (wm == hh) {
            #pragma unroll
            for (int fm = 0; fm < 4; fm++)
                #pragma unroll
                for (int fn = 0; fn < 4; fn++)
                    #pragma unroll
                    for (int r = 0; r < 4; r++)
                        Cs[fm*16 + g*4 + r][wn*64 + fn*16 + qr] = acc[fm][fn][r];
        }
        __syncthreads();
        float vals[32];
        #pragma unroll
        for (int j = 0; j < 32; j++) vals[j] = Cs[erow][c0 + j] + bias[n0 + c0 + j];
        const int tl = tl0 + hh*64 + erow;
        if (MODE == 0) {
            const int by = blockIdx.y;
            short* dst = (by < 2) ? oq : ok;
            const float qs = (by < 2) ? QSCALE : 1.0f;
            const int h = (by & 1)*2 + (c0 >> 6);
            const int d0 = c0 & 63;
            short8 s0, s1;
            #pragma unroll
            for (int j = 0; j < 8; j++) {
                s0[j] = f2bf(vals[j]*qs);
                s1[j] = f2bf(vals[8+j]*qs);
            }
            short8 s2, s3;
            #pragma unroll
            for (int j = 0; j < 8; j++) {
                s2[j] = f2bf(vals[16+j]*qs);
                s3[j] = f2bf(vals[24+j]*qs);
            }
            short* p = dst + ((size_t)(b*H + h)*T + tl)*HD + d0;
            *(short8*)p = s0;
            *(short8*)(p + 8) = s1;
            *(short8*)(p + 16) = s2;
            *(short8*)(p + 24) = s3;
        } else {   // MODE 2: relu -> bf16 mid [m][1024]
            short8 s0, s1, s2, s3;
            #pragma unroll
            for (int j = 0; j < 8; j++) {
                s0[j] = f2bf(fmaxf(vals[j],    0.f));
                s1[j] = f2bf(fmaxf(vals[8+j],  0.f));
                s2[j] = f2bf(fmaxf(vals[16+j], 0.f));
                s3[j] = f2bf(fmaxf(vals[24+j], 0.f));
            }
            short* p = o16 + (size_t)(m0 + hh*64 + erow)*1024 + n0 + c0;
            *(short8*)p = s0;
            *(short8*)(p + 8) = s1;
            *(short8*)(p + 16) = s2;
            *(short8*)(p + 24) = s3;
        }
        if (hh == 0) __syncthreads();
    }
}

// ---------------- K_GEMM: 64x64 LDS-staged (kept for N=256 GEMMs) ----------
template<int MODE>
__global__ __launch_bounds__(256) void k_gemm(
        const short* __restrict__ A, const short* __restrict__ W,
        const float* __restrict__ bias, const int K,
        float* __restrict__ of) {
    __shared__ short As[64][72];
    __shared__ short Ws[64][72];
    __shared__ float Cs[64][68];
    const int tid = threadIdx.x;
    const int w = tid >> 6, lane = tid & 63;
    const int qr = lane & 15, g = lane >> 4;
    const int wm = w >> 1, wn = w & 1;
    const int m0 = blockIdx.x * 64;
    const int n0 = blockIdx.y * 64;
    const int srow = tid >> 2, scol = (tid & 3) * 8;
    const short* Ag = A + (size_t)(m0 + srow) * K + scol;
    const short* Wg = W + (size_t)(n0 + srow) * K + scol;

    f32x4 acc[2][2];
    #pragma unroll
    for (int i = 0; i < 2; i++)
        #pragma unroll
        for (int j = 0; j < 2; j++) acc[i][j] = (f32x4){0.f, 0.f, 0.f, 0.f};

    for (int k0 = 0; k0 < K; k0 += 64) {
        __syncthreads();
        *(short8*)&As[srow][scol]      = *(const short8*)(Ag + k0);
        *(short8*)&As[srow][scol + 32] = *(const short8*)(Ag + k0 + 32);
        *(short8*)&Ws[srow][scol]      = *(const short8*)(Wg + k0);
        *(short8*)&Ws[srow][scol + 32] = *(const short8*)(Wg + k0 + 32);
        __syncthreads();
        #pragma unroll
        for (int kk = 0; kk < 2; kk++) {
            short8 a0 = *(const short8*)&As[wm*32 + qr][g*8 + kk*32];
            short8 a1 = *(const short8*)&As[wm*32 + 16 + qr][g*8 + kk*32];
            short8 b0 = *(const short8*)&Ws[wn*32 + qr][g*8 + kk*32];
            short8 b1 = *(const short8*)&Ws[wn*32 + 16 + qr][g*8 + kk*32];
            acc[0][0] = __builtin_amdgcn_mfma_f32_16x16x32_bf16(a0, b0, acc[0][0], 0, 0, 0);
            acc[0][1] = __builtin_amdgcn_mfma_f32_16x16x32_bf16(a0, b1, acc[0][1], 0, 0, 0);
            acc[1][0] = __builtin_amdgcn_mfma_f32_16x16x32_bf16(a1, b0, acc[1][0], 0, 0, 0);
            acc[1][1] = __builtin_amdgcn_mfma_f32_16x16x32_bf16(a1, b1, acc[1][1], 0, 0, 0);
        }
    }

    #pragma unroll
    for (int fm = 0; fm < 2; fm++)
        #pragma unroll
        for (int fn = 0; fn < 2; fn++)
            #pragma unroll
            for (int r = 0; r < 4; r++)
                Cs[wm*32 + fm*16 + g*4 + r][wn*32 + fn*16 + qr] = acc[fm][fn][r];
    __syncthreads();
    const int row = tid >> 2, c0 = (tid & 3) * 16;
    float vals[16];
    #pragma unroll
    for (int j = 0; j < 16; j++) vals[j] = Cs[row][c0 + j] + bias[n0 + c0 + j];
    float* p = of + (size_t)(m0 + row)*256 + n0 + c0;
    #pragma unroll
    for (int jj = 0; jj < 4; jj++) *(float4*)(p + jj*4) = *(float4*)&vals[jj*4];
}

// ---------------- FL: l-only pass (unchanged from R8) ----------------------
__global__ __launch_bounds__(256) void k_flashL(
        const short* __restrict__ qb, const short* __restrict__ kb,
        const float* __restrict__ mask, float* __restrict__ liout) {
    __shared__ short Ks[128][72];
    __shared__ float lbuf[4][4][16];
    const int tid = threadIdx.x;
    const int w = tid >> 6, lane = tid & 63;
    const int qr = lane & 15, g = lane >> 4;
    const int qt = blockIdx.x, h = blockIdx.y, b = blockIdx.z;
    const int bh = b*H + h;
    const int q0 = qt*64;

    short8 qf[4][2];
    {
        const short* qg = qb + ((size_t)bh * T + q0) * HD;
        #pragma unroll
        for (int qt4 = 0; qt4 < 4; qt4++) {
            qf[qt4][0] = *(const short8*)(qg + (qt4*16 + qr)*HD + g*8);
            qf[qt4][1] = *(const short8*)(qg + (qt4*16 + qr)*HD + 32 + g*8);
        }
    }
    const short* kg0 = kb + (size_t)bh * T * HD;
    const float* mg  = mask + (size_t)b * T;
    const int krow = lane >> 1, khalf = (lane & 1) * 32;

    float lrun[4] = {0.f, 0.f, 0.f, 0.f};

    for (int kt = 0; kt < 16; kt++) {
        const int kbase = kt*128 + w*32;
        {
            const short* ksrc = kg0 + (size_t)(kbase + krow)*HD + khalf;
            short* kdst = &Ks[w*32 + krow][khalf];
            #pragma unroll
            for (int c = 0; c < 4; c++)
                *(short8*)(kdst + c*8) = *(const short8*)(ksrc + c*8);
        }
        asm volatile("" ::: "memory");
        #pragma unroll
        for (int kt2 = 0; kt2 < 2; kt2++) {
            short8 kf0 = *(const short8*)&Ks[w*32 + kt2*16 + qr][g*8];
            short8 kf1 = *(const short8*)&Ks[w*32 + kt2*16 + qr][g*8 + 32];
            const int key0 = kbase + kt2*16;
            const float4 mv4 = *(const float4*)(mg + key0 + 4*g);
            const float b0 = (mv4.x > 0.5f) ? -1e9f : 0.f;
            const float b1 = (mv4.y > 0.5f) ? -1e9f : 0.f;
            const float b2v = (mv4.z > 0.5f) ? -1e9f : 0.f;
            const float b3 = (mv4.w > 0.5f) ? -1e9f : 0.f;
            #pragma unroll
            for (int qt4 = 0; qt4 < 4; qt4++) {
                f32x4 sa = (f32x4){b0, b1, b2v, b3};
                sa = __builtin_amdgcn_mfma_f32_16x16x32_bf16(kf0, qf[qt4][0], sa, 0, 0, 0);
                sa = __builtin_amdgcn_mfma_f32_16x16x32_bf16(kf1, qf[qt4][1], sa, 0, 0, 0);
                lrun[qt4] += (exp2a(sa[0]) + exp2a(sa[1])) + (exp2a(sa[2]) + exp2a(sa[3]));
            }
        }
        asm volatile("" ::: "memory");
    }
    #pragma unroll
    for (int qt4 = 0; qt4 < 4; qt4++) {
        lrun[qt4] += __shfl_xor(lrun[qt4], 16, 64);
        lrun[qt4] += __shfl_xor(lrun[qt4], 32, 64);
    }
    if (g == 0) {
        #pragma unroll
        for (int qt4 = 0; qt4 < 4; qt4++) lbuf[w][qt4][qr] = lrun[qt4];
    }
    __syncthreads();
    if (tid < 64) {
        const int qt4 = tid >> 4, qrr = tid & 15;
        const float l = lbuf[0][qt4][qrr] + lbuf[1][qt4][qrr]
                      + lbuf[2][qt4][qrr] + lbuf[3][qt4][qrr];
        liout[(size_t)bh*T + q0 + tid] = -__log2f(l);
    }
}

// ---------------- FATTN: unchanged from R8 ---------------------------------
__global__ __launch_bounds__(256) void k_fattn(
        const short* __restrict__ qb, const short* __restrict__ kb,
        const short* __restrict__ vtb, const float* __restrict__ mask,
        const float* __restrict__ liout,
        short* __restrict__ attnb, float* __restrict__ part4) {
    __shared__ short Ks[128][72];
    __shared__ short Vt[64][136];
    __shared__ short Ps[4][64][40];
    const int tid = threadIdx.x;
    const int w = tid >> 6, lane = tid & 63;
    const int qr = lane & 15, g = lane >> 4;
    const int qt = blockIdx.x, h = blockIdx.y, b = blockIdx.z;
    const int bh = b*H + h;
    const int q0 = qt*64;

    short8 qf[4][2];
    float li[4];
    {
        const short* qg = qb + ((size_t)bh * T + q0) * HD;
        #pragma unroll
        for (int qt4 = 0; qt4 < 4; qt4++) {
            qf[qt4][0] = *(const short8*)(qg + (qt4*16 + qr)*HD + g*8);
            qf[qt4][1] = *(const short8*)(qg + (qt4*16 + qr)*HD + 32 + g*8);
            li[qt4] = liout[(size_t)bh*T + q0 + qt4*16 + qr];
        }
    }
    const short* kg0 = kb + (size_t)bh * T * HD;
    const short* vg0 = vtb + (size_t)bh * HD * T;
    const float* mg  = mask + (size_t)b * T;
    float* csrow = part4 + (size_t)(bh*32 + qt) * T;
    const int krow = lane >> 1, khalf = (lane & 1) * 32;

    f32x4 oa[4][4];
    #pragma unroll
    for (int nt = 0; nt < 4; nt++)
        #pragma unroll
        for (int qt4 = 0; qt4 < 4; qt4++) oa[nt][qt4] = (f32x4){0.f,0.f,0.f,0.f};

    short8 kreg[4], vreg[4];
    #pragma unroll
    for (int c = 0; c < 4; c++) {
        kreg[c] = *(const short8*)(kg0 + (size_t)(w*32 + krow)*HD + khalf + c*8);
        vreg[c] = *(const short8*)(vg0 + (size_t)lane*T + w*32 + c*8);
    }
    #pragma unroll
    for (int c = 0; c < 4; c++) {
        *(short8*)&Ks[w*32 + krow][khalf + c*8] = kreg[c];
        *(short8*)&Vt[lane][w*32 + c*8] = vreg[c];
    }
    asm volatile("" ::: "memory");

    for (int kt = 0; kt < 16; kt++) {
        if (kt < 15) {
            const int nb = (kt+1)*128 + w*32;
            #pragma unroll
            for (int c = 0; c < 4; c++) {
                kreg[c] = *(const short8*)(kg0 + (size_t)(nb + krow)*HD + khalf + c*8);
                vreg[c] = *(const short8*)(vg0 + (size_t)lane*T + nb + c*8);
            }
        }
        const int kbase = kt*128 + w*32;
        #pragma unroll
        for (int kt2 = 0; kt2 < 2; kt2++) {
            short8 kf0 = *(const short8*)&Ks[w*32 + kt2*16 + qr][g*8];
            short8 kf1 = *(const short8*)&Ks[w*32 + kt2*16 + qr][g*8 + 32];
            const int key0 = kbase + kt2*16;
            const float4 mv4 = *(const float4*)(mg + key0 + 4*g);
            const float mb[4] = { (mv4.x > 0.5f) ? -1e9f : 0.f,
                                  (mv4.y > 0.5f) ? -1e9f : 0.f,
                                  (mv4.z > 0.5f) ? -1e9f : 0.f,
                                  (mv4.w > 0.5f) ? -1e9f : 0.f };
            float p[4][4];
            #pragma unroll
            for (int qt4 = 0; qt4 < 4; qt4++) {
                f32x4 sa = (f32x4){mb[0] + li[qt4], mb[1] + li[qt4],
                                   mb[2] + li[qt4], mb[3] + li[qt4]};
                sa = __builtin_amdgcn_mfma_f32_16x16x32_bf16(kf0, qf[qt4][0], sa, 0, 0, 0);
                sa = __builtin_amdgcn_mfma_f32_16x16x32_bf16(kf1, qf[qt4][1], sa, 0, 0, 0);
                p[qt4][0] = exp2a(sa[0]); p[qt4][1] = exp2a(sa[1]);
                p[qt4][2] = exp2a(sa[2]); p[qt4][3] = exp2a(sa[3]);
            }
            float cs[4];
            #pragma unroll
            for (int r = 0; r < 4; r++) {
                cs[r] = (p[0][r] + p[1][r]) + (p[2][r] + p[3][r]);
                cs[r] += __shfl_xor(cs[r], 1, 64);
                cs[r] += __shfl_xor(cs[r], 2, 64);
                cs[r] += __shfl_xor(cs[r], 4, 64);
                cs[r] += __shfl_xor(cs[r], 8, 64);
            }
            if (qr == 0) {
                #pragma unroll
                for (int r = 0; r < 4; r++) csrow[key0 + 4*g + r] = cs[r];
            }
            #pragma unroll
            for (int qt4 = 0; qt4 < 4; qt4++) {
                union { unsigned u[2]; s16x4 s; } cv;
                cv.u[0] = cvtpk(p[qt4][0], p[qt4][1]);
                cv.u[1] = cvtpk(p[qt4][2], p[qt4][3]);
                *(s16x4*)&Ps[w][qt4*16 + qr][kt2*16 + 4*g] = cv.s;
            }
        }
        asm volatile("" ::: "memory");
        short8 pa[4];
        #pragma unroll
        for (int qt4 = 0; qt4 < 4; qt4++)
            pa[qt4] = *(const short8*)&Ps[w][qt4*16 + qr][g*8];
        #pragma unroll
        for (int nt = 0; nt < 4; nt++) {
            short8 vf = *(const short8*)&Vt[nt*16 + qr][w*32 + g*8];
            #pragma unroll
            for (int qt4 = 0; qt4 < 4; qt4++)
                oa[nt][qt4] = __builtin_amdgcn_mfma_f32_16x16x32_bf16(vf, pa[qt4], oa[nt][qt4], 0, 0, 0);
        }
        if (kt < 15) {
            asm volatile("" ::: "memory");
            #pragma unroll
            for (int c = 0; c < 4; c++) {
                *(short8*)&Ks[w*32 + krow][khalf + c*8] = kreg[c];
                *(short8*)&Vt[lane][w*32 + c*8] = vreg[c];
            }
            asm volatile("" ::: "memory");
        }
    }

    __syncthreads();
    float* Obuf = (float*)&Ks[0][0];
    const int qL = tid >> 2, dq = tid & 3;
    #pragma unroll
    for (int nt = 0; nt < 4; nt++) {
        #pragma unroll
        for (int qt4 = 0; qt4 < 4; qt4++)
            #pragma unroll
            for (int r = 0; r < 4; r++)
                Obuf[(w*16 + 4*g + r)*68 + qt4*16 + qr] = oa[nt][qt4][r];
        __syncthreads();
        s16x4 pk;
        #pragma unroll
        for (int rr = 0; rr < 4; rr++) {
            const int dr = dq*4 + rr;
            float v = Obuf[(0*16 + dr)*68 + qL] + Obuf[(1*16 + dr)*68 + qL]
                    + Obuf[(2*16 + dr)*68 + qL] + Obuf[(3*16 + dr)*68 + qL];
            pk[rr] = f2bf(v);
        }
        *(s16x4*)&attnb[((size_t)b*T + q0 + qL)*D + h*HD + nt*16 + dq*4] = pk;
        __syncthreads();
    }
}

// ---------------- K_RED / K_HALT / K_LN (unchanged) ------------------------
__global__ __launch_bounds__(256) void k_red(
        const float* __restrict__ part, float* __restrict__ red) {
    __shared__ float s[128];
    const int b = blockIdx.y, kc = blockIdx.x;
    const int tid = threadIdx.x;
    const int c = tid & 127, half = tid >> 7;
    const int k = kc*128 + c;
    const float* pb = part + ((size_t)(b*128 + half*64))*T + k;
    float acc = 0.f;
    #pragma unroll 8
    for (int r = 0; r < 64; r++) acc += pb[(size_t)r*T];
    if (half) s[c] = acc;
    __syncthreads();
    if (!half) red[(size_t)b*T + k] = acc + s[c];
}

__global__ __launch_bounds__(256) void k_halt(
        const float* __restrict__ red, const float* __restrict__ mask,
        float* __restrict__ outh) {
    __shared__ float redm[4], reds[4];
    const int b = blockIdx.x, tid = threadIdx.x;
    const float* mg = mask + (size_t)b * T;
    float v[8];
    float M = -3e38f;
    #pragma unroll
    for (int i = 0; i < 8; i++) {
        v[i] = red[(size_t)b*T + tid + i*256]*0.25f + mg[tid + i*256]*(-1e10f);
        M = fmaxf(M, v[i]);
    }
    #pragma unroll
    for (int off = 1; off < 64; off <<= 1) M = fmaxf(M, __shfl_xor(M, off, 64));
    const int wv = tid >> 6, lane = tid & 63;
    if (lane == 0) redm[wv] = M;
    __syncthreads();
    M = fmaxf(fmaxf(redm[0], redm[1]), fmaxf(redm[2], redm[3]));
    float S = 0.f;
    #pragma unroll
    for (int i = 0; i < 8; i++) { v[i] = __expf(v[i] - M); S += v[i]; }
    #pragma unroll
    for (int off = 1; off < 64; off <<= 1) S += __shfl_xor(S, off, 64);
    if (lane == 0) reds[wv] = S;
    __syncthreads();
    const float invS = 1.f / (reds[0] + reds[1] + reds[2] + reds[3]);
    #pragma unroll
    for (int i = 0; i < 8; i++) outh[(size_t)b*T + tid + i*256] = v[i]*invS;
}

__global__ __launch_bounds__(256) void k_ln(
        const float* __restrict__ a, const float* __restrict__ bsrc,
        const float* __restrict__ g, const float* __restrict__ be,
        float* __restrict__ yf, short* __restrict__ y16) {
    __shared__ float s[16][D];
    const int tid = threadIdx.x;
    const size_t row0 = (size_t)blockIdx.x * 16;
    const float4* ag = (const float4*)(a + row0*D);
    const float4* bg = (const float4*)(bsrc + row0*D);
    #pragma unroll
    for (int i = 0; i < 4; i++) {
        float4 av = ag[tid + i*256], bv = bg[tid + i*256];
        float4 sv = {av.x+bv.x, av.y+bv.y, av.z+bv.z, av.w+bv.w};
        ((float4*)&s[0][0])[tid + i*256] = sv;
    }
    __syncthreads();
    const int wv = tid >> 6, lane = tid & 63;
    float gvv[4], bvv[4];
    #pragma unroll
    for (int s2 = 0; s2 < 4; s2++) { gvv[s2] = g[lane + 64*s2]; bvv[s2] = be[lane + 64*s2]; }
    #pragma unroll
    for (int rr = 0; rr < 4; rr++) {
        const int r = wv*4 + rr;
        float x0 = s[r][lane],     x1 = s[r][lane+64];
        float x2 = s[r][lane+128], x3 = s[r][lane+192];
        float sum = x0+x1+x2+x3;
        float ssq = x0*x0 + x1*x1 + x2*x2 + x3*x3;
        #pragma unroll
        for (int off = 1; off < 64; off <<= 1) {
            sum += __shfl_xor(sum, off, 64);
            ssq += __shfl_xor(ssq, off, 64);
        }
        const float mu = sum * (1.f/256.f);
        const float rs = rsqrtf(ssq*(1.f/256.f) - mu*mu + 1e-5f);
        float y0 = (x0 - mu)*rs*gvv[0] + bvv[0];
        float y1 = (x1 - mu)*rs*gvv[1] + bvv[1];
        float y2 = (x2 - mu)*rs*gvv[2] + bvv[2];
        float y3 = (x3 - mu)*rs*gvv[3] + bvv[3];
        float* yp = yf + (row0 + r)*D;
        yp[lane]     = y0;
        yp[lane+64]  = y1;
        yp[lane+128] = y2;
        yp[lane+192] = y3;
        if (y16) {
            short* hp = y16 + (row0 + r)*D;
            hp[lane]     = f2bf(y0);
            hp[lane+64]  = f2bf(y1);
            hp[lane+128] = f2bf(y2);
            hp[lane+192] = f2bf(y3);
        }
    }
}

} // namespace

extern "C" void kernel_launch(void* const* d_in, const int* in_sizes, int n_in,
                              void* d_out, int out_size, void* d_ws, size_t ws_size,
                              hipStream_t stream) {
    (void)in_sizes; (void)n_in; (void)out_size; (void)ws_size;
    const float* x    = (const float*)d_in[0];
    const float* mask = (const float*)d_in[1];
    const float* Wqkv = (const float*)d_in[2];
    const float* bqkv = (const float*)d_in[3];
    const float* Wo   = (const float*)d_in[4];
    const float* bo   = (const float*)d_in[5];
    const float* W1   = (const float*)d_in[6];
    const float* b1   = (const float*)d_in[7];
    const float* W2   = (const float*)d_in[8];
    const float* b2   = (const float*)d_in[9];
    const float* g1   = (const float*)d_in[10];
    const float* be1  = (const float*)d_in[11];
    const float* g2   = (const float*)d_in[12];
    const float* be2  = (const float*)d_in[13];

    float* out  = (float*)d_out;
    char*  wsb  = (char*)d_ws;
    const size_t MB = 1024*1024;

    short* qb16   = (short*)(wsb + 0*MB);
    short* kb16   = (short*)(wsb + 8*MB);
    short* vt16   = (short*)(wsb + 16*MB);
    short* x16    = (short*)(wsb + 24*MB);
    short* attn16 = (short*)(wsb + 24*MB);
    short* mid16  = (short*)(wsb + 0*MB);
    float* part4  = (float*)(wsb + 32*MB);
    float* redb   = (float*)(wsb + 40*MB);
    float* liout  = (float*)(wsb + 41*MB);
    short* wq16   = (short*)(wsb + 42*MB);
    short* wo16   = (short*)(wsb + 42*MB + 393216);
    short* w116   = (short*)(wsb + 42*MB + 524288);
    short* w216   = (short*)(wsb + 42*MB + 1048576);
    float* hb     = (float*)(wsb + 44*MB);
    short* h16    = (short*)(wsb + 60*MB);
    float* po     = (float*)(wsb + 68*MB);
    float* fo     = (float*)(wsb + 68*MB);
    float* outh   = out + (size_t)B*T*D;

    k_cvt      <<<dim3(1024),       256, 0, stream>>>(x, Wqkv, Wo, W1, W2,
                                                      x16, wq16, wo16, w116, w216);
    k_gemm128<0><<<dim3(128, 6),    256, 0, stream>>>(x16, wq16, bqkv, 256,
                                                      qb16, kb16, vt16, nullptr);
    k_flashL   <<<dim3(32, H, B),   256, 0, stream>>>(qb16, kb16, mask, liout);
    k_fattn    <<<dim3(32, H, B),   256, 0, stream>>>(qb16, kb16, vt16, mask, liout,
                                                      attn16, part4);
    k_red      <<<dim3(16, B),      256, 0, stream>>>(part4, redb);
    k_halt     <<<dim3(B),          256, 0, stream>>>(redb, mask, outh);
    k_gemm<1>  <<<dim3(256, 4),     256, 0, stream>>>(attn16, wo16, bo, 256, po);
    k_ln       <<<dim3(B*T/16),     256, 0, stream>>>(x, po, g1, be1, hb, h16);
    k_gemm128<2><<<dim3(128, 8),    256, 0, stream>>>(h16, w116, b1, 256,
                                                      nullptr, nullptr, nullptr, mid16);
    k_gemm<3>  <<<dim3(256, 4),     256, 0, stream>>>(mid16, w216, b2, 1024, fo);
    k_ln       <<<dim3(B*T/16),     256, 0, stream>>>(hb, fo, g2, be2, out, nullptr);
}